// Round 10
// baseline (727.435 us; speedup 1.0000x reference)
//
#include <hip/hip_runtime.h>
#include <math.h>

#define B_ 4
#define T_ 1024
#define E_ 1024
#define H_ 16
#define HD_ 64

constexpr float SCALE_ = 0.125f;              // HD^-0.5
constexpr float PI_F = 3.14159265358979323846f;

constexpr size_t BTE = (size_t)B_ * T_ * E_;  // 4M
constexpr size_t BTT = (size_t)B_ * T_ * T_;  // 4M
constexpr int M_ = B_ * T_;                   // 4096
constexpr int KC_ = 2 * E_;                   // 2048 (concat r|i)

typedef __attribute__((ext_vector_type(8))) short bf16x8;
typedef __attribute__((ext_vector_type(4))) float f32x4;

__device__ __forceinline__ short f2bf(float f) {
    unsigned int u = __float_as_uint(f);
    unsigned int r = (u + 0x7fffu + ((u >> 16) & 1u)) >> 16;
    return (short)r;
}
__device__ __forceinline__ float bf2f(short s) {
    return __uint_as_float(((unsigned int)(unsigned short)s) << 16);
}
__device__ __forceinline__ void fsplit(float v, short& h, short& l) {
    short hh = f2bf(v);
    h = hh;
    l = f2bf(v - bf2f(hh));
}
__device__ __forceinline__ void gl_lds16(const void* g, void* l) {
    __builtin_amdgcn_global_load_lds(
        (const __attribute__((address_space(1))) unsigned int*)g,
        (__attribute__((address_space(3))) unsigned int*)l, 16, 0, 0);
}

// ---------------------------------------------------------------- stacked bf16 weights (single)
__global__ __launch_bounds__(256) void wgen(const float* __restrict__ lm,
                                            const float* __restrict__ ph,
                                            short* __restrict__ W) {
    int idx = blockIdx.x * 256 + threadIdx.x;   // over E*E
    int n = idx >> 10, k = idx & 1023;
    float m = expf(lm[idx]);
    float s, c;
    sincosf(ph[idx], &s, &c);
    float wr = m * c, wi = m * s;
    size_t r0 = (size_t)n * KC_;
    size_t r1 = (size_t)(n + 1024) * KC_;
    W[r0 + k]        = f2bf(wr);
    W[r0 + 1024 + k] = f2bf(-wi);
    W[r1 + k]        = f2bf(wi);
    W[r1 + 1024 + k] = f2bf(wr);
}

// ---------------------------------------------------------------- stacked bf16 weights (hi/lo split)
__global__ __launch_bounds__(256) void wgen_split(const float* __restrict__ lm,
                                                  const float* __restrict__ ph,
                                                  short* __restrict__ Wh,
                                                  short* __restrict__ Wl) {
    int idx = blockIdx.x * 256 + threadIdx.x;
    int n = idx >> 10, k = idx & 1023;
    float m = expf(lm[idx]);
    float s, c;
    sincosf(ph[idx], &s, &c);
    float wr = m * c, wi = m * s;
    size_t o0 = (size_t)n * KC_ + k;
    size_t o1 = (size_t)n * KC_ + 1024 + k;
    size_t o2 = (size_t)(n + 1024) * KC_ + k;
    size_t o3 = (size_t)(n + 1024) * KC_ + 1024 + k;
    short h, l;
    fsplit(wr,  h, l); Wh[o0] = h; Wl[o0] = l;
    fsplit(-wi, h, l); Wh[o1] = h; Wl[o1] = l;
    fsplit(wi,  h, l); Wh[o2] = h; Wl[o2] = l;
    fsplit(wr,  h, l); Wh[o3] = h; Wl[o3] = l;
}

// ---------------------------------------------------------------- x concat -> bf16 hi/lo
__global__ __launch_bounds__(256) void xcat_split(const float* __restrict__ xr,
                                                  const float* __restrict__ xi,
                                                  short* __restrict__ xh,
                                                  short* __restrict__ xl) {
    size_t idx = (size_t)blockIdx.x * 256 + threadIdx.x;  // BTE
    size_t m = idx >> 10, k = idx & 1023;
    short h, l;
    fsplit(xr[idx], h, l);
    xh[m * KC_ + k] = h; xl[m * KC_ + k] = l;
    fsplit(xi[idx], h, l);
    xh[m * KC_ + 1024 + k] = h; xl[m * KC_ + 1024 + k] = l;
}

// ---------------------------------------------------------------- geodesic bias table (bf16)
__global__ __launch_bounds__(256) void geodist(const float* __restrict__ lat,
                                               const float* __restrict__ lon,
                                               short* __restrict__ ld) {
    size_t idx = (size_t)blockIdx.x * 256 + threadIdx.x;   // over B*T*T
    int k = (int)(idx & (T_ - 1));
    int q = (int)((idx >> 10) & (T_ - 1));
    int b = (int)(idx >> 20);
    float la1 = (lat[b * T_ + q] - 90.f) * (PI_F / 180.f);
    float la2 = (lat[b * T_ + k] - 90.f) * (PI_F / 180.f);
    float lo1 = lon[b * T_ + q] * (PI_F / 180.f);
    float lo2 = lon[b * T_ + k] * (PI_F / 180.f);
    float sdla = sinf((la2 - la1) * 0.5f);
    float sdlo = sinf((lo2 - lo1) * 0.5f);
    float a = sdla * sdla + cosf(la1) * cosf(la2) * sdlo * sdlo;
    a = fminf(fmaxf(a, 0.f), 1.f);
    float dd = 2.f * asinf(sqrtf(a)) * (180.f / PI_F);
    ld[idx] = f2bf(log1pf(dd));
}

// ---------------------------------------------------------------- split-bf16 Q-or-K GEMM + fused RoPE
// cgemm_mfma structure (measured ~750 TF): 128x128 tile, 4 waves, 2x32KB dbuf
// (2 blocks/CU -> independent barrier domains), stage-at-top + one __syncthreads.
// Per buffer: [A: 1024 chunks (hi 0-3 | lo 4-7 per row)][W: 1024 chunks], XOR swizzle.
// Block id>>9 selects Q (0) or K (1).
__global__ __launch_bounds__(256, 2) void cgemm_qk_split(const short* __restrict__ Ah,
                                                         const short* __restrict__ Al,
                                                         const short* __restrict__ Qwh,
                                                         const short* __restrict__ Qwl,
                                                         const short* __restrict__ Kwh,
                                                         const short* __restrict__ Kwl,
                                                         const float* __restrict__ qbm,
                                                         const float* __restrict__ qbp,
                                                         const float* __restrict__ kbm,
                                                         const float* __restrict__ kbp,
                                                         short* __restrict__ Qh,
                                                         short* __restrict__ Ql,
                                                         short* __restrict__ Kh,
                                                         short* __restrict__ Kl) {
    __shared__ short lds[2][2048 * 8];   // 2 x 32 KB

    const int tid = threadIdx.x;
    const int w = tid >> 6, l = tid & 63;
    const int wm = w >> 1, wn = w & 1;
    const int wl = l & 15, g = l >> 4;

    const int id = blockIdx.x;           // 0..1023
    const int sel = id >> 9;             // 0 = Q, 1 = K
    const int p = id & 511;
    const int x = p & 7;                 // XCD-blocked: xcd covers 8bm x 8bn
    const int jj = p >> 3;               // 0..63
    const int bm = ((x & 3) * 8 + (jj & 7)) * 128;
    const int bn = ((x >> 2) * 8 + (jj >> 3)) * 128;

    const short* Wh = sel ? Kwh : Qwh;
    const short* Wl2 = sel ? Kwl : Qwl;

    f32x4 acc[4][4];
#pragma unroll
    for (int m = 0; m < 4; ++m)
#pragma unroll
        for (int n = 0; n < 4; ++n) acc[m][n] = (f32x4){0.f, 0.f, 0.f, 0.f};

    auto stage = [&](int k0, int buf) {   // 8 gl_lds per thread
#pragma unroll
        for (int i = 0; i < 8; ++i) {
            const int c = i * 256 + tid;          // 0..2047
            short* dst = &lds[buf][(size_t)c * 8];
            if (c < 1024) {
                const int row = c >> 3, c8 = (c & 7) ^ (row & 7);
                gl_lds16(((c8 < 4) ? Ah : Al) + (size_t)(bm + row) * KC_ + k0 + (c8 & 3) * 8, dst);
            } else {
                const int lc = c - 1024, row = lc >> 3, c8 = (lc & 7) ^ (row & 7);
                gl_lds16(((c8 < 4) ? Wh : Wl2) + (size_t)(bn + row) * KC_ + k0 + (c8 & 3) * 8, dst);
            }
        }
    };

    const int NT = KC_ / 32;             // 64
    stage(0, 0);
    __syncthreads();

    int cur = 0;
    for (int t = 0; t < NT; ++t) {
        if (t + 1 < NT) stage((t + 1) * 32, cur ^ 1);

        const short* sA = &lds[cur][0];
        const short* sW = &lds[cur][1024 * 8];

        bf16x8 afh[4], afl[4], wfh[4], wfl[4];
#pragma unroll
        for (int m = 0; m < 4; ++m) {
            const int ra = wm * 64 + m * 16 + wl;
            const int sw = ra & 7;
            afh[m] = *(const bf16x8*)&sA[(ra * 8 + (g ^ sw)) * 8];
            afl[m] = *(const bf16x8*)&sA[(ra * 8 + ((g + 4) ^ sw)) * 8];
        }
#pragma unroll
        for (int n = 0; n < 4; ++n) {
            const int rb = wn * 64 + n * 16 + wl;
            const int sw = rb & 7;
            wfh[n] = *(const bf16x8*)&sW[(rb * 8 + (g ^ sw)) * 8];
            wfl[n] = *(const bf16x8*)&sW[(rb * 8 + ((g + 4) ^ sw)) * 8];
        }
#pragma unroll
        for (int n = 0; n < 4; ++n)
#pragma unroll
            for (int m = 0; m < 4; ++m) {
                acc[m][n] = __builtin_amdgcn_mfma_f32_16x16x32_bf16(afh[m], wfh[n], acc[m][n], 0, 0, 0);
                acc[m][n] = __builtin_amdgcn_mfma_f32_16x16x32_bf16(afh[m], wfl[n], acc[m][n], 0, 0, 0);
                acc[m][n] = __builtin_amdgcn_mfma_f32_16x16x32_bf16(afl[m], wfh[n], acc[m][n], 0, 0, 0);
            }

        __syncthreads();
        cur ^= 1;
    }

    const float* bmag = sel ? kbm : qbm;
    const float* bphs = sel ? kbp : qbp;
    short* Oh = sel ? Kh : Qh;
    short* Ol = sel ? Kl : Ql;

    // bias add
#pragma unroll
    for (int n = 0; n < 4; ++n) {
        const int col = bn + wn * 64 + n * 16 + wl;
        const int ch = col & 1023;
        float sb, cb;
        sincosf(bphs[ch], &sb, &cb);
        const float bias = bmag[ch] * (col < 1024 ? cb : sb);
#pragma unroll
        for (int m = 0; m < 4; ++m)
#pragma unroll
            for (int r = 0; r < 4; ++r) acc[m][n][r] += bias;
    }

    // fused RoPE: pairs (n, n+2); freq j = n*16+wl
#pragma unroll
    for (int n = 0; n < 2; ++n) {
        const int jf = n * 16 + wl;
        const float invf = expf(-(2.f * jf / 64.f) * 9.210340371976184f);
#pragma unroll
        for (int m = 0; m < 4; ++m)
#pragma unroll
            for (int r = 0; r < 4; ++r) {
                const int row = bm + wm * 64 + m * 16 + g * 4 + r;
                const float th = (float)(row & 1023) * invf;
                float s_, c_;
                sincosf(th, &s_, &c_);
                const float x1 = acc[m][n][r], x2 = acc[m][n + 2][r];
                acc[m][n][r]     = x1 * c_ - x2 * s_;
                acc[m][n + 2][r] = x2 * c_ + x1 * s_;
            }
    }

    // split store, head-concat layout
#pragma unroll
    for (int n = 0; n < 4; ++n) {
        const int col = bn + wn * 64 + n * 16 + wl;
        const int ch = col & 1023;
        const int off = (ch >> 6) * 128 + (ch & 63) + ((col >= 1024) ? 64 : 0);
#pragma unroll
        for (int m = 0; m < 4; ++m)
#pragma unroll
            for (int r = 0; r < 4; ++r) {
                const int row = bm + wm * 64 + m * 16 + g * 4 + r;
                short h_, l_;
                fsplit(acc[m][n][r], h_, l_);
                Oh[(size_t)row * KC_ + off] = h_;
                Ol[(size_t)row * KC_ + off] = l_;
            }
    }
}

// ---------------------------------------------------------------- single-bf16 MFMA GEMM (V, O)
// r6 form: 128x128 tile, 4 waves, double-buffered 2x16KB interleaved A|W, syncthreads loop.
__global__ __launch_bounds__(256) void cgemm_mfma(const short* __restrict__ A,
                                                  const short* __restrict__ W,
                                                  const float* __restrict__ bmag,
                                                  const float* __restrict__ bphase,
                                                  short* __restrict__ outbf,
                                                  float* __restrict__ outr,
                                                  float* __restrict__ outi,
                                                  int mode) {
    __shared__ short lds[2][1024 * 8];   // 2 x 16 KB

    const int tid = threadIdx.x;
    const int w = tid >> 6, l = tid & 63;
    const int wm = w >> 1, wn = w & 1;
    const int wl = l & 15, g = l >> 4;

    int id = blockIdx.y * 32 + blockIdx.x;
    int swz = (id & 7) * 64 + (id >> 3);
    const int bm = (swz & 31) * 128;
    const int bn = (swz >> 5) * 128;

    f32x4 acc[4][4];
#pragma unroll
    for (int m = 0; m < 4; ++m)
#pragma unroll
        for (int n = 0; n < 4; ++n) acc[m][n] = (f32x4){0.f, 0.f, 0.f, 0.f};

    auto stage = [&](int k0, int buf) {
#pragma unroll
        for (int i = 0; i < 4; ++i) {
            const int c = i * 256 + tid;       // 0..1023
            const int row = c >> 3, c8 = (c & 7) ^ (row & 7);
            const short* src = (c8 < 4)
                ? A + (size_t)(bm + row) * KC_ + k0 + (c8 & 3) * 8
                : W + (size_t)(bn + row) * KC_ + k0 + (c8 & 3) * 8;
            gl_lds16(src, &lds[buf][(size_t)c * 8]);
        }
    };

    const int NT = KC_ / 32;
    stage(0, 0);
    __syncthreads();

    int cur = 0;
    for (int t = 0; t < NT; ++t) {
        if (t + 1 < NT) stage((t + 1) * 32, cur ^ 1);

        const short* sAB = lds[cur];
        bf16x8 af[4], bfr[4];
#pragma unroll
        for (int m = 0; m < 4; ++m) {
            const int ra = wm * 64 + m * 16 + wl;
            af[m] = *(const bf16x8*)&sAB[(ra * 8 + (g ^ (ra & 7))) * 8];
        }
#pragma unroll
        for (int n = 0; n < 4; ++n) {
            const int rb = wn * 64 + n * 16 + wl;
            bfr[n] = *(const bf16x8*)&sAB[(rb * 8 + ((g + 4) ^ (rb & 7))) * 8];
        }
#pragma unroll
        for (int m = 0; m < 4; ++m)
#pragma unroll
            for (int n = 0; n < 4; ++n)
                acc[m][n] = __builtin_amdgcn_mfma_f32_16x16x32_bf16(af[m], bfr[n], acc[m][n], 0, 0, 0);

        __syncthreads();
        cur ^= 1;
    }

#pragma unroll
    for (int n = 0; n < 4; ++n) {
        const int col = bn + wn * 64 + n * 16 + wl;
        const int ch = col & 1023;
        float sb, cb;
        sincosf(bphase[ch], &sb, &cb);
        const float bias = bmag[ch] * (col < 1024 ? cb : sb);
#pragma unroll
        for (int m = 0; m < 4; ++m) {
#pragma unroll
            for (int r = 0; r < 4; ++r) {
                const int row = bm + wm * 64 + m * 16 + g * 4 + r;
                const float v = acc[m][n][r] + bias;
                if (mode == 0) {
                    const int hh = ch >> 6, d = ch & 63;
                    outbf[(size_t)row * KC_ + hh * 128 + d + ((col >= 1024) ? 64 : 0)] = f2bf(v);
                } else {
                    if (col < 1024) outr[(size_t)row * E_ + col] = v;
                    else            outi[(size_t)row * E_ + (col - 1024)] = v;
                }
            }
        }
    }
}

// ---------------------------------------------------------------- MFMA flash attention
// 1D grid of 512 blocks, 512 threads (8 waves). QBLK=128, KVBLK=64. (r6 form)
__global__ __launch_bounds__(512) void attn_split(const short* __restrict__ qh,
                                                  const short* __restrict__ ql,
                                                  const short* __restrict__ kh,
                                                  const short* __restrict__ kl,
                                                  const short* __restrict__ vc,
                                                  const short* __restrict__ ldb,
                                                  const float* __restrict__ dsc,
                                                  const float* __restrict__ dof,
                                                  short* __restrict__ otc) {
    __shared__ short sKh[64 * 128];       // swizzled 16B chunks (full 4-bit XOR)
    __shared__ short sKl[64 * 128];
    __shared__ short sV[2][64 * 66];      // [comp][d][66] (V transposed)
    __shared__ short sP[8][16 * 68];      // per-wave P [qlocal][68]

    const int j = blockIdx.x;
    const int h = j & 15;
    const int idx = j >> 4;               // 0..31
    const int b = idx & 3;
    const int q4 = idx >> 2;              // 0..7
    const int qt = (q4 < 4) ? (7 - q4) : (q4 - 4);   // pairs (7,0),(6,1),(5,2),(4,3)

    const int tid = threadIdx.x;
    const int w = tid >> 6, l = tid & 63;
    const int wl = l & 15, g = l >> 4;

    const float dsch = dsc[h], dofh = dof[h];

    // Q hi/lo fragments: rows q = qt*128 + w*16 + wl
    bf16x8 aqh[4], aql[4];
    {
        const size_t qbase = ((size_t)(b * T_) + qt * 128 + w * 16 + wl) * KC_ + h * 128;
#pragma unroll
        for (int ks = 0; ks < 4; ++ks) {
            aqh[ks] = *(const bf16x8*)(qh + qbase + ks * 32 + g * 8);
            aql[ks] = *(const bf16x8*)(ql + qbase + ks * 32 + g * 8);
        }
    }

    f32x4 accR[4], accI[4];
#pragma unroll
    for (int nb = 0; nb < 4; ++nb) {
        accR[nb] = (f32x4){0.f, 0.f, 0.f, 0.f};
        accI[nb] = (f32x4){0.f, 0.f, 0.f, 0.f};
    }
    float m_run[4], l_run[4];
#pragma unroll
    for (int r = 0; r < 4; ++r) { m_run[r] = -3.0e38f; l_run[r] = 0.f; }

    const int nkt = 2 * qt + 2;
    for (int kt = 0; kt < nkt; ++kt) {
        __syncthreads();

        // stage K hi/lo: linear dest, inverse-swizzled per-lane source (4-bit XOR)
#pragma unroll
        for (int i = 0; i < 2; ++i) {
            int chunk = (w * 2 + i) * 64 + l;
            int row = chunk >> 4;
            int c8 = (chunk & 15) ^ (row & 15);
            size_t src = ((size_t)(b * T_) + kt * 64 + row) * KC_ + h * 128 + c8 * 8;
            gl_lds16(kh + src, sKh + (w * 2 + i) * 64 * 8);
            gl_lds16(kl + src, sKl + (w * 2 + i) * 64 * 8);
        }
        // stage V transposed: lane = token; wave w covers comp = w>>2, dims [(w&3)*16, +16)
        {
            const short* vrow = vc + ((size_t)(b * T_) + kt * 64 + l) * KC_ + h * 128;
            const int comp = w >> 2;
            const int d0 = (w & 3) * 16;
#pragma unroll
            for (int half = 0; half < 2; ++half) {
                bf16x8 v8 = *(const bf16x8*)(vrow + comp * 64 + d0 + half * 8);
#pragma unroll
                for (int jj = 0; jj < 8; ++jj) sV[comp][(d0 + half * 8 + jj) * 66 + l] = v8[jj];
            }
        }
        __syncthreads();

        // QK^T split: hh + hl + lh
        f32x4 s[4];
#pragma unroll
        for (int nb = 0; nb < 4; ++nb) s[nb] = (f32x4){0.f, 0.f, 0.f, 0.f};
#pragma unroll
        for (int nb = 0; nb < 4; ++nb) {
            const int ktl = nb * 16 + wl;
#pragma unroll
            for (int ks = 0; ks < 4; ++ks) {
                const int pc8 = (ks * 4 + g) ^ (ktl & 15);
                const bf16x8 bkh = *(const bf16x8*)&sKh[ktl * 128 + pc8 * 8];
                const bf16x8 bkl = *(const bf16x8*)&sKl[ktl * 128 + pc8 * 8];
                s[nb] = __builtin_amdgcn_mfma_f32_16x16x32_bf16(aqh[ks], bkh, s[nb], 0, 0, 0);
                s[nb] = __builtin_amdgcn_mfma_f32_16x16x32_bf16(aqh[ks], bkl, s[nb], 0, 0, 0);
                s[nb] = __builtin_amdgcn_mfma_f32_16x16x32_bf16(aql[ks], bkh, s[nb], 0, 0, 0);
            }
        }

        // scale + geo bias (bf16 table) + causal mask
        const int qg0 = qt * 128 + w * 16 + g * 4;
        const int kg0 = kt * 64;
        const bool domask = (kt >= 2 * qt);
#pragma unroll
        for (int nb = 0; nb < 4; ++nb) {
            const int kg = kg0 + nb * 16 + wl;
            const short* ldp = ldb + ((size_t)b * T_ + qg0) * T_ + kg;
#pragma unroll
            for (int r = 0; r < 4; ++r) {
                float sv = s[nb][r] * SCALE_ + dsch * bf2f(ldp[(size_t)r * T_]) + dofh;
                if (domask && kg > qg0 + r) sv = -1.0e9f;
                s[nb][r] = sv;
            }
        }

        // online softmax
#pragma unroll
        for (int r = 0; r < 4; ++r) {
            float mt = fmaxf(fmaxf(s[0][r], s[1][r]), fmaxf(s[2][r], s[3][r]));
            mt = fmaxf(mt, __shfl_xor(mt, 1));
            mt = fmaxf(mt, __shfl_xor(mt, 2));
            mt = fmaxf(mt, __shfl_xor(mt, 4));
            mt = fmaxf(mt, __shfl_xor(mt, 8));
            const float mnew = fmaxf(m_run[r], mt);
            const float sc = __expf(m_run[r] - mnew);
            m_run[r] = mnew;
            float rs = 0.f;
#pragma unroll
            for (int nb = 0; nb < 4; ++nb) {
                const float p = __expf(s[nb][r] - mnew);
                s[nb][r] = p;
                rs += p;
            }
            rs += __shfl_xor(rs, 1);
            rs += __shfl_xor(rs, 2);
            rs += __shfl_xor(rs, 4);
            rs += __shfl_xor(rs, 8);
            l_run[r] = l_run[r] * sc + rs;
#pragma unroll
            for (int nb = 0; nb < 4; ++nb) { accR[nb][r] *= sc; accI[nb][r] *= sc; }
        }

        // P -> LDS (wave-private), then PV
#pragma unroll
        for (int nb = 0; nb < 4; ++nb)
#pragma unroll
            for (int r = 0; r < 4; ++r)
                sP[w][(g * 4 + r) * 68 + nb * 16 + wl] = f2bf(s[nb][r]);

        bf16x8 ap[2];
#pragma unroll
        for (int ks = 0; ks < 2; ++ks)
            ap[ks] = *(const bf16x8*)&sP[w][wl * 68 + ks * 32 + g * 8];
#pragma unroll
        for (int nb = 0; nb < 4; ++nb) {
#pragma unroll
            for (int ks = 0; ks < 2; ++ks) {
                const bf16x8 bvr = *(const bf16x8*)&sV[0][(nb * 16 + wl) * 66 + ks * 32 + g * 8];
                const bf16x8 bvi = *(const bf16x8*)&sV[1][(nb * 16 + wl) * 66 + ks * 32 + g * 8];
                accR[nb] = __builtin_amdgcn_mfma_f32_16x16x32_bf16(ap[ks], bvr, accR[nb], 0, 0, 0);
                accI[nb] = __builtin_amdgcn_mfma_f32_16x16x32_bf16(ap[ks], bvi, accI[nb], 0, 0, 0);
            }
        }
    }

    // epilogue
    float inv[4];
#pragma unroll
    for (int r = 0; r < 4; ++r) inv[r] = 1.0f / l_run[r];
#pragma unroll
    for (int nb = 0; nb < 4; ++nb) {
#pragma unroll
        for (int r = 0; r < 4; ++r) {
            const int q = qt * 128 + w * 16 + g * 4 + r;
            const int d = nb * 16 + wl;
            const size_t base = ((size_t)(b * T_) + q) * KC_ + h * 64 + d;
            otc[base] = f2bf(accR[nb][r] * inv[r]);
            otc[base + 1024] = f2bf(accI[nb][r] * inv[r]);
        }
    }
}

// ---------------------------------------------------------------- launch
extern "C" void kernel_launch(void* const* d_in, const int* in_sizes, int n_in,
                              void* d_out, int out_size, void* d_ws, size_t ws_size,
                              hipStream_t stream) {
    const float* x_r  = (const float*)d_in[0];
    const float* x_i  = (const float*)d_in[1];
    const float* lat  = (const float*)d_in[2];
    const float* lon  = (const float*)d_in[3];
    const float* q_lm = (const float*)d_in[4];
    const float* q_ph = (const float*)d_in[5];
    const float* q_bm = (const float*)d_in[6];
    const float* q_bp = (const float*)d_in[7];
    const float* k_lm = (const float*)d_in[8];
    const float* k_ph = (const float*)d_in[9];
    const float* k_bm = (const float*)d_in[10];
    const float* k_bp = (const float*)d_in[11];
    const float* v_lm = (const float*)d_in[12];
    const float* v_ph = (const float*)d_in[13];
    const float* v_bm = (const float*)d_in[14];
    const float* v_bp = (const float*)d_in[15];
    const float* o_lm = (const float*)d_in[16];
    const float* o_ph = (const float*)d_in[17];
    const float* o_bm = (const float*)d_in[18];
    const float* o_bp = (const float*)d_in[19];
    const float* dsc  = (const float*)d_in[20];
    const float* dof  = (const float*)d_in[21];

    char* ws = (char*)d_ws;
    const size_t MB = 1024u * 1024u;
    short* Wv  = (short*)(ws + 0 * MB);     // 8 MB
    short* Wo  = (short*)(ws + 8 * MB);     // 8 MB
    short* Wqh = (short*)(ws + 16 * MB);    // 8 MB
    short* Wql = (short*)(ws + 24 * MB);
    short* Wkh = (short*)(ws + 32 * MB);
    short* Wkl = (short*)(ws + 40 * MB);
    short* xch = (short*)(ws + 48 * MB);    // 16 MB
    short* xcl = (short*)(ws + 64 * MB);    // 16 MB
    short* qhh = (short*)(ws + 80 * MB);    // 16 MB
    short* qll = (short*)(ws + 96 * MB);
    short* khh = (short*)(ws + 112 * MB);
    short* kll = (short*)(ws + 128 * MB);
    short* vcb = (short*)(ws + 144 * MB);   // 16 MB
    short* otc = (short*)(ws + 160 * MB);   // 16 MB
    short* ldt = (short*)(ws + 176 * MB);   // B*T*T bf16, 8 MB

    wgen_split<<<(E_ * E_) / 256, 256, 0, stream>>>(q_lm, q_ph, Wqh, Wql);
    wgen_split<<<(E_ * E_) / 256, 256, 0, stream>>>(k_lm, k_ph, Wkh, Wkl);
    wgen<<<(E_ * E_) / 256, 256, 0, stream>>>(v_lm, v_ph, Wv);
    wgen<<<(E_ * E_) / 256, 256, 0, stream>>>(o_lm, o_ph, Wo);
    xcat_split<<<BTE / 256, 256, 0, stream>>>(x_r, x_i, xch, xcl);
    geodist<<<BTT / 256, 256, 0, stream>>>(lat, lon, ldt);

    cgemm_qk_split<<<1024, 256, 0, stream>>>(xch, xcl, Wqh, Wql, Wkh, Wkl,
                                             q_bm, q_bp, k_bm, k_bp,
                                             qhh, qll, khh, kll);

    dim3 ggrid(M_ / 128, KC_ / 128);
    cgemm_mfma<<<ggrid, 256, 0, stream>>>(xch, Wv, v_bm, v_bp, vcb, nullptr, nullptr, 0);

    attn_split<<<512, 512, 0, stream>>>(qhh, qll, khh, kll, vcb, ldt, dsc, dof, otc);

    float* yr = (float*)d_out;
    float* yi = (float*)d_out + BTE;
    cgemm_mfma<<<ggrid, 256, 0, stream>>>(otc, Wo, o_bm, o_bp, nullptr, yr, yi, 1);
}

// Round 11
// 591.760 us; speedup vs baseline: 1.2293x; 1.2293x over previous
//
#include <hip/hip_runtime.h>
#include <math.h>

#define B_ 4
#define T_ 1024
#define E_ 1024
#define H_ 16
#define HD_ 64

constexpr float SCALE_ = 0.125f;              // HD^-0.5
constexpr float PI_F = 3.14159265358979323846f;

constexpr size_t BTE = (size_t)B_ * T_ * E_;  // 4M
constexpr size_t BTT = (size_t)B_ * T_ * T_;  // 4M
constexpr int M_ = B_ * T_;                   // 4096
constexpr int KC_ = 2 * E_;                   // 2048 (concat r|i)

typedef __attribute__((ext_vector_type(8))) short bf16x8;
typedef __attribute__((ext_vector_type(4))) float f32x4;

__device__ __forceinline__ short f2bf(float f) {
    unsigned int u = __float_as_uint(f);
    unsigned int r = (u + 0x7fffu + ((u >> 16) & 1u)) >> 16;
    return (short)r;
}
__device__ __forceinline__ float bf2f(short s) {
    return __uint_as_float(((unsigned int)(unsigned short)s) << 16);
}
__device__ __forceinline__ void fsplit(float v, short& h, short& l) {
    short hh = f2bf(v);
    h = hh;
    l = f2bf(v - bf2f(hh));
}
__device__ __forceinline__ void gl_lds16(const void* g, void* l) {
    __builtin_amdgcn_global_load_lds(
        (const __attribute__((address_space(1))) unsigned int*)g,
        (__attribute__((address_space(3))) unsigned int*)l, 16, 0, 0);
}

// ---------------------------------------------------------------- all stacked bf16 weights, one launch
// which = blockIdx.x>>12: 0 = Q (hi/lo split), 1 = K (split), 2 = V (plain), 3 = O (plain)
__global__ __launch_bounds__(256) void wgen_all(const float* __restrict__ qlm, const float* __restrict__ qph,
                                                const float* __restrict__ klm, const float* __restrict__ kph,
                                                const float* __restrict__ vlm, const float* __restrict__ vph,
                                                const float* __restrict__ olm, const float* __restrict__ oph,
                                                short* __restrict__ Wqh, short* __restrict__ Wql,
                                                short* __restrict__ Wkh, short* __restrict__ Wkl,
                                                short* __restrict__ Wv,  short* __restrict__ Wo) {
    const int which = blockIdx.x >> 12;
    const int idx = (blockIdx.x & 4095) * 256 + threadIdx.x;   // over E*E
    const int n = idx >> 10, k = idx & 1023;
    const float* lm = (which == 0) ? qlm : (which == 1) ? klm : (which == 2) ? vlm : olm;
    const float* ph = (which == 0) ? qph : (which == 1) ? kph : (which == 2) ? vph : oph;
    float m = expf(lm[idx]);
    float s, c;
    sincosf(ph[idx], &s, &c);
    const float wr = m * c, wi = m * s;
    const size_t o0 = (size_t)n * KC_ + k;
    const size_t o1 = (size_t)n * KC_ + 1024 + k;
    const size_t o2 = (size_t)(n + 1024) * KC_ + k;
    const size_t o3 = (size_t)(n + 1024) * KC_ + 1024 + k;
    if (which < 2) {
        short* Wh = which ? Wkh : Wqh;
        short* Wl = which ? Wkl : Wql;
        short h, l;
        fsplit(wr,  h, l); Wh[o0] = h; Wl[o0] = l;
        fsplit(-wi, h, l); Wh[o1] = h; Wl[o1] = l;
        fsplit(wi,  h, l); Wh[o2] = h; Wl[o2] = l;
        fsplit(wr,  h, l); Wh[o3] = h; Wl[o3] = l;
    } else {
        short* W = (which == 2) ? Wv : Wo;
        W[o0] = f2bf(wr);
        W[o1] = f2bf(-wi);
        W[o2] = f2bf(wi);
        W[o3] = f2bf(wr);
    }
}

// ---------------------------------------------------------------- x concat -> bf16 hi/lo
__global__ __launch_bounds__(256) void xcat_split(const float* __restrict__ xr,
                                                  const float* __restrict__ xi,
                                                  short* __restrict__ xh,
                                                  short* __restrict__ xl) {
    size_t idx = (size_t)blockIdx.x * 256 + threadIdx.x;  // BTE
    size_t m = idx >> 10, k = idx & 1023;
    short h, l;
    fsplit(xr[idx], h, l);
    xh[m * KC_ + k] = h; xl[m * KC_ + k] = l;
    fsplit(xi[idx], h, l);
    xh[m * KC_ + 1024 + k] = h; xl[m * KC_ + 1024 + k] = l;
}

// ---------------------------------------------------------------- geodesic bias table (bf16)
__global__ __launch_bounds__(256) void geodist(const float* __restrict__ lat,
                                               const float* __restrict__ lon,
                                               short* __restrict__ ld) {
    size_t idx = (size_t)blockIdx.x * 256 + threadIdx.x;   // over B*T*T
    int k = (int)(idx & (T_ - 1));
    int q = (int)((idx >> 10) & (T_ - 1));
    int b = (int)(idx >> 20);
    float la1 = (lat[b * T_ + q] - 90.f) * (PI_F / 180.f);
    float la2 = (lat[b * T_ + k] - 90.f) * (PI_F / 180.f);
    float lo1 = lon[b * T_ + q] * (PI_F / 180.f);
    float lo2 = lon[b * T_ + k] * (PI_F / 180.f);
    float sdla = sinf((la2 - la1) * 0.5f);
    float sdlo = sinf((lo2 - lo1) * 0.5f);
    float a = sdla * sdla + cosf(la1) * cosf(la2) * sdlo * sdlo;
    a = fminf(fmaxf(a, 0.f), 1.f);
    float dd = 2.f * asinf(sqrtf(a)) * (180.f / PI_F);
    ld[idx] = f2bf(log1pf(dd));
}

// ---------------------------------------------------------------- fused split-bf16 Q+K GEMM + RoPE
// Best-measured structure (335 us): 8 waves, BM=256, BN=128, BK=32, 2x64KB dbuf,
// stage(t+1) at loop top, one __syncthreads per K-step, XCD-blocked 256-block grid.
__global__ __launch_bounds__(512, 2) void cgemm_qk2(const short* __restrict__ Ah,
                                                    const short* __restrict__ Al,
                                                    const short* __restrict__ Qwh,
                                                    const short* __restrict__ Qwl,
                                                    const short* __restrict__ Kwh,
                                                    const short* __restrict__ Kwl,
                                                    const float* __restrict__ qbm,
                                                    const float* __restrict__ qbp,
                                                    const float* __restrict__ kbm,
                                                    const float* __restrict__ kbp,
                                                    short* __restrict__ Qh,
                                                    short* __restrict__ Ql,
                                                    short* __restrict__ Kh,
                                                    short* __restrict__ Kl) {
    __shared__ short lds[2][4096 * 8];   // 2 x 64 KB

    const int tid = threadIdx.x;
    const int w = tid >> 6, l = tid & 63;
    const int wm = w >> 1;               // 0..3 -> rows [wm*64, +64)
    const int wn = w & 1;                // 0..1 -> cols [wn*64, +64)
    const int wl = l & 15, g = l >> 4;

    // XCD-blocked decode: xcd x covers 4 bm x 8 bn (perf-only heuristic)
    const int id = blockIdx.x;           // 0..255
    const int x = id & 7;
    const int j = id >> 3;               // 0..31
    const int bm = ((x & 3) * 4 + (j & 3)) * 256;
    const int bnc = ((x >> 2) * 8 + (j >> 2)) * 128;

    f32x4 accQ[4][4], accK[4][4];
#pragma unroll
    for (int m = 0; m < 4; ++m)
#pragma unroll
        for (int n = 0; n < 4; ++n) {
            accQ[m][n] = (f32x4){0.f, 0.f, 0.f, 0.f};
            accK[m][n] = (f32x4){0.f, 0.f, 0.f, 0.f};
        }

    auto stage = [&](int k0, int buf) {   // 8 gl_lds per thread per call
#pragma unroll
        for (int i = 0; i < 8; ++i) {
            const int c = i * 512 + tid;          // 0..4095
            short* dst = &lds[buf][(size_t)c * 8];
            if (c < 2048) {
                const int row = c >> 3, c8 = (c & 7) ^ (row & 7);
                gl_lds16(((c8 < 4) ? Ah : Al) + (size_t)(bm + row) * KC_ + k0 + (c8 & 3) * 8, dst);
            } else if (c < 3072) {
                const int lc = c - 2048, row = lc >> 3, c8 = (lc & 7) ^ (row & 7);
                gl_lds16(((c8 < 4) ? Qwh : Qwl) + (size_t)(bnc + row) * KC_ + k0 + (c8 & 3) * 8, dst);
            } else {
                const int lc = c - 3072, row = lc >> 3, c8 = (lc & 7) ^ (row & 7);
                gl_lds16(((c8 < 4) ? Kwh : Kwl) + (size_t)(bnc + row) * KC_ + k0 + (c8 & 3) * 8, dst);
            }
        }
    };

    const int NT = KC_ / 32;             // 64
    stage(0, 0);
    __syncthreads();

    int cur = 0;
    for (int t = 0; t < NT; ++t) {
        if (t + 1 < NT) stage((t + 1) * 32, cur ^ 1);

        const short* sA = &lds[cur][0];
        const short* sQ = &lds[cur][2048 * 8];
        const short* sK = &lds[cur][3072 * 8];

        bf16x8 afh[4], afl[4];
#pragma unroll
        for (int m = 0; m < 4; ++m) {
            const int ra = wm * 64 + m * 16 + wl;
            const int sw = ra & 7;
            afh[m] = *(const bf16x8*)&sA[(ra * 8 + (g ^ sw)) * 8];
            afl[m] = *(const bf16x8*)&sA[(ra * 8 + ((g + 4) ^ sw)) * 8];
        }
#pragma unroll
        for (int n = 0; n < 4; ++n) {
            const int rb = wn * 64 + n * 16 + wl;
            const int sw = rb & 7;
            const bf16x8 qh_ = *(const bf16x8*)&sQ[(rb * 8 + (g ^ sw)) * 8];
            const bf16x8 ql_ = *(const bf16x8*)&sQ[(rb * 8 + ((g + 4) ^ sw)) * 8];
            const bf16x8 kh_ = *(const bf16x8*)&sK[(rb * 8 + (g ^ sw)) * 8];
            const bf16x8 kl_ = *(const bf16x8*)&sK[(rb * 8 + ((g + 4) ^ sw)) * 8];
#pragma unroll
            for (int m = 0; m < 4; ++m) {
                accQ[m][n] = __builtin_amdgcn_mfma_f32_16x16x32_bf16(afh[m], qh_, accQ[m][n], 0, 0, 0);
                accQ[m][n] = __builtin_amdgcn_mfma_f32_16x16x32_bf16(afh[m], ql_, accQ[m][n], 0, 0, 0);
                accQ[m][n] = __builtin_amdgcn_mfma_f32_16x16x32_bf16(afl[m], qh_, accQ[m][n], 0, 0, 0);
                accK[m][n] = __builtin_amdgcn_mfma_f32_16x16x32_bf16(afh[m], kh_, accK[m][n], 0, 0, 0);
                accK[m][n] = __builtin_amdgcn_mfma_f32_16x16x32_bf16(afh[m], kl_, accK[m][n], 0, 0, 0);
                accK[m][n] = __builtin_amdgcn_mfma_f32_16x16x32_bf16(afl[m], kh_, accK[m][n], 0, 0, 0);
            }
        }
        __syncthreads();   // vmcnt(0) drain here -> t+1 stage landed
        cur ^= 1;
    }

    // bias add (Q and K)
#pragma unroll
    for (int n = 0; n < 4; ++n) {
        const int col = bnc + wn * 64 + n * 16 + wl;
        const int ch = col & 1023;
        float qs, qc, ks, kc;
        sincosf(qbp[ch], &qs, &qc);
        sincosf(kbp[ch], &ks, &kc);
        const float qbias = qbm[ch] * (col < 1024 ? qc : qs);
        const float kbias = kbm[ch] * (col < 1024 ? kc : ks);
#pragma unroll
        for (int m = 0; m < 4; ++m)
#pragma unroll
            for (int r = 0; r < 4; ++r) {
                accQ[m][n][r] += qbias;
                accK[m][n][r] += kbias;
            }
    }

    // fused RoPE: pairs (n, n+2); freq j = n*16+wl; same angle for Q and K
#pragma unroll
    for (int n = 0; n < 2; ++n) {
        const int jf = n * 16 + wl;
        const float invf = expf(-(2.f * jf / 64.f) * 9.210340371976184f);
#pragma unroll
        for (int m = 0; m < 4; ++m)
#pragma unroll
            for (int r = 0; r < 4; ++r) {
                const int row = bm + wm * 64 + m * 16 + g * 4 + r;
                const float th = (float)(row & 1023) * invf;
                float s_, c_;
                sincosf(th, &s_, &c_);
                float x1 = accQ[m][n][r], x2 = accQ[m][n + 2][r];
                accQ[m][n][r]     = x1 * c_ - x2 * s_;
                accQ[m][n + 2][r] = x2 * c_ + x1 * s_;
                x1 = accK[m][n][r]; x2 = accK[m][n + 2][r];
                accK[m][n][r]     = x1 * c_ - x2 * s_;
                accK[m][n + 2][r] = x2 * c_ + x1 * s_;
            }
    }

    // split store, head-concat layout
#pragma unroll
    for (int n = 0; n < 4; ++n) {
        const int col = bnc + wn * 64 + n * 16 + wl;
        const int ch = col & 1023;
        const int off = (ch >> 6) * 128 + (ch & 63) + ((col >= 1024) ? 64 : 0);
#pragma unroll
        for (int m = 0; m < 4; ++m)
#pragma unroll
            for (int r = 0; r < 4; ++r) {
                const int row = bm + wm * 64 + m * 16 + g * 4 + r;
                short h_, l_;
                fsplit(accQ[m][n][r], h_, l_);
                Qh[(size_t)row * KC_ + off] = h_;
                Ql[(size_t)row * KC_ + off] = l_;
                fsplit(accK[m][n][r], h_, l_);
                Kh[(size_t)row * KC_ + off] = h_;
                Kl[(size_t)row * KC_ + off] = l_;
            }
    }
}

// ---------------------------------------------------------------- single-bf16 MFMA GEMM (V, O)
// 128x128 tile, 4 waves, double-buffered 2x16KB interleaved A|W buffer, 2-phase pipeline.
__global__ __launch_bounds__(256) void cgemm_mfma(const short* __restrict__ A,
                                                  const short* __restrict__ W,
                                                  const float* __restrict__ bmag,
                                                  const float* __restrict__ bphase,
                                                  short* __restrict__ outbf,
                                                  float* __restrict__ outr,
                                                  float* __restrict__ outi,
                                                  int mode) {
    __shared__ short lds[2][1024 * 8];   // 2 x 16 KB

    const int tid = threadIdx.x;
    const int w = tid >> 6, l = tid & 63;
    const int wm = w >> 1, wn = w & 1;
    const int wl = l & 15, g = l >> 4;

    int id = blockIdx.y * 32 + blockIdx.x;
    int swz = (id & 7) * 64 + (id >> 3);
    const int bm = (swz & 31) * 128;
    const int bn = (swz >> 5) * 128;

    f32x4 acc[4][4];
#pragma unroll
    for (int m = 0; m < 4; ++m)
#pragma unroll
        for (int n = 0; n < 4; ++n) acc[m][n] = (f32x4){0.f, 0.f, 0.f, 0.f};

    auto stage = [&](int k0, int buf) {
#pragma unroll
        for (int i = 0; i < 4; ++i) {
            const int c = i * 256 + tid;       // 0..1023
            const int row = c >> 3, c8 = (c & 7) ^ (row & 7);
            const short* src = (c8 < 4)
                ? A + (size_t)(bm + row) * KC_ + k0 + (c8 & 3) * 8
                : W + (size_t)(bn + row) * KC_ + k0 + (c8 & 3) * 8;
            gl_lds16(src, &lds[buf][(size_t)c * 8]);
        }
    };

    const int NT = KC_ / 32;
    stage(0, 0);
    __syncthreads();

    int cur = 0;
    for (int t = 0; t < NT; ++t) {
        if (t + 1 < NT) stage((t + 1) * 32, cur ^ 1);

        const short* sAB = lds[cur];
        bf16x8 af[4], bfr[4];
#pragma unroll
        for (int m = 0; m < 4; ++m) {
            const int ra = wm * 64 + m * 16 + wl;
            af[m] = *(const bf16x8*)&sAB[(ra * 8 + (g ^ (ra & 7))) * 8];
        }
#pragma unroll
        for (int n = 0; n < 4; ++n) {
            const int rb = wn * 64 + n * 16 + wl;
            bfr[n] = *(const bf16x8*)&sAB[(rb * 8 + ((g + 4) ^ (rb & 7))) * 8];
        }
#pragma unroll
        for (int m = 0; m < 4; ++m)
#pragma unroll
            for (int n = 0; n < 4; ++n)
                acc[m][n] = __builtin_amdgcn_mfma_f32_16x16x32_bf16(af[m], bfr[n], acc[m][n], 0, 0, 0);

        __syncthreads();
        cur ^= 1;
    }

#pragma unroll
    for (int n = 0; n < 4; ++n) {
        const int col = bn + wn * 64 + n * 16 + wl;
        const int ch = col & 1023;
        float sb, cb;
        sincosf(bphase[ch], &sb, &cb);
        const float bias = bmag[ch] * (col < 1024 ? cb : sb);
#pragma unroll
        for (int m = 0; m < 4; ++m) {
#pragma unroll
            for (int r = 0; r < 4; ++r) {
                const int row = bm + wm * 64 + m * 16 + g * 4 + r;
                const float v = acc[m][n][r] + bias;
                if (mode == 0) {
                    const int hh = ch >> 6, d = ch & 63;
                    outbf[(size_t)row * KC_ + hh * 128 + d + ((col >= 1024) ? 64 : 0)] = f2bf(v);
                } else {
                    if (col < 1024) outr[(size_t)row * E_ + col] = v;
                    else            outi[(size_t)row * E_ + (col - 1024)] = v;
                }
            }
        }
    }
}

// ---------------------------------------------------------------- MFMA flash attention
// 1D grid of 512 blocks, 512 threads (8 waves). QBLK=128, KVBLK=64.
// 2 blocks/CU (independent phases) -> s_setprio(1) around MFMA clusters (T5, m191 regime).
__global__ __launch_bounds__(512) void attn_split(const short* __restrict__ qh,
                                                  const short* __restrict__ ql,
                                                  const short* __restrict__ kh,
                                                  const short* __restrict__ kl,
                                                  const short* __restrict__ vc,
                                                  const short* __restrict__ ldb,
                                                  const float* __restrict__ dsc,
                                                  const float* __restrict__ dof,
                                                  short* __restrict__ otc) {
    __shared__ short sKh[64 * 128];       // swizzled 16B chunks (full 4-bit XOR)
    __shared__ short sKl[64 * 128];
    __shared__ short sV[2][64 * 66];      // [comp][d][66] (V transposed)
    __shared__ short sP[8][16 * 68];      // per-wave P [qlocal][68]

    const int j = blockIdx.x;
    const int h = j & 15;
    const int idx = j >> 4;               // 0..31
    const int b = idx & 3;
    const int q4 = idx >> 2;              // 0..7
    const int qt = (q4 < 4) ? (7 - q4) : (q4 - 4);   // pairs (7,0),(6,1),(5,2),(4,3)

    const int tid = threadIdx.x;
    const int w = tid >> 6, l = tid & 63;
    const int wl = l & 15, g = l >> 4;

    const float dsch = dsc[h], dofh = dof[h];

    // Q hi/lo fragments: rows q = qt*128 + w*16 + wl
    bf16x8 aqh[4], aql[4];
    {
        const size_t qbase = ((size_t)(b * T_) + qt * 128 + w * 16 + wl) * KC_ + h * 128;
#pragma unroll
        for (int ks = 0; ks < 4; ++ks) {
            aqh[ks] = *(const bf16x8*)(qh + qbase + ks * 32 + g * 8);
            aql[ks] = *(const bf16x8*)(ql + qbase + ks * 32 + g * 8);
        }
    }

    f32x4 accR[4], accI[4];
#pragma unroll
    for (int nb = 0; nb < 4; ++nb) {
        accR[nb] = (f32x4){0.f, 0.f, 0.f, 0.f};
        accI[nb] = (f32x4){0.f, 0.f, 0.f, 0.f};
    }
    float m_run[4], l_run[4];
#pragma unroll
    for (int r = 0; r < 4; ++r) { m_run[r] = -3.0e38f; l_run[r] = 0.f; }

    const int nkt = 2 * qt + 2;
    for (int kt = 0; kt < nkt; ++kt) {
        __syncthreads();

        // stage K hi/lo: linear dest, inverse-swizzled per-lane source (4-bit XOR)
#pragma unroll
        for (int i = 0; i < 2; ++i) {
            int chunk = (w * 2 + i) * 64 + l;
            int row = chunk >> 4;
            int c8 = (chunk & 15) ^ (row & 15);
            size_t src = ((size_t)(b * T_) + kt * 64 + row) * KC_ + h * 128 + c8 * 8;
            gl_lds16(kh + src, sKh + (w * 2 + i) * 64 * 8);
            gl_lds16(kl + src, sKl + (w * 2 + i) * 64 * 8);
        }
        // stage V transposed: lane = token; wave w covers comp = w>>2, dims [(w&3)*16, +16)
        {
            const short* vrow = vc + ((size_t)(b * T_) + kt * 64 + l) * KC_ + h * 128;
            const int comp = w >> 2;
            const int d0 = (w & 3) * 16;
#pragma unroll
            for (int half = 0; half < 2; ++half) {
                bf16x8 v8 = *(const bf16x8*)(vrow + comp * 64 + d0 + half * 8);
#pragma unroll
                for (int jj = 0; jj < 8; ++jj) sV[comp][(d0 + half * 8 + jj) * 66 + l] = v8[jj];
            }
        }
        __syncthreads();

        // QK^T split: hh + hl + lh
        f32x4 s[4];
#pragma unroll
        for (int nb = 0; nb < 4; ++nb) s[nb] = (f32x4){0.f, 0.f, 0.f, 0.f};
        __builtin_amdgcn_s_setprio(1);
#pragma unroll
        for (int nb = 0; nb < 4; ++nb) {
            const int ktl = nb * 16 + wl;
#pragma unroll
            for (int ks = 0; ks < 4; ++ks) {
                const int pc8 = (ks * 4 + g) ^ (ktl & 15);
                const bf16x8 bkh = *(const bf16x8*)&sKh[ktl * 128 + pc8 * 8];
                const bf16x8 bkl = *(const bf16x8*)&sKl[ktl * 128 + pc8 * 8];
                s[nb] = __builtin_amdgcn_mfma_f32_16x16x32_bf16(aqh[ks], bkh, s[nb], 0, 0, 0);
                s[nb] = __builtin_amdgcn_mfma_f32_16x16x32_bf16(aqh[ks], bkl, s[nb], 0, 0, 0);
                s[nb] = __builtin_amdgcn_mfma_f32_16x16x32_bf16(aql[ks], bkh, s[nb], 0, 0, 0);
            }
        }
        __builtin_amdgcn_s_setprio(0);

        // scale + geo bias (bf16 table) + causal mask
        const int qg0 = qt * 128 + w * 16 + g * 4;
        const int kg0 = kt * 64;
        const bool domask = (kt >= 2 * qt);
#pragma unroll
        for (int nb = 0; nb < 4; ++nb) {
            const int kg = kg0 + nb * 16 + wl;
            const short* ldp = ldb + ((size_t)b * T_ + qg0) * T_ + kg;
#pragma unroll
            for (int r = 0; r < 4; ++r) {
                float sv = s[nb][r] * SCALE_ + dsch * bf2f(ldp[(size_t)r * T_]) + dofh;
                if (domask && kg > qg0 + r) sv = -1.0e9f;
                s[nb][r] = sv;
            }
        }

        // online softmax
#pragma unroll
        for (int r = 0; r < 4; ++r) {
            float mt = fmaxf(fmaxf(s[0][r], s[1][r]), fmaxf(s[2][r], s[3][r]));
            mt = fmaxf(mt, __shfl_xor(mt, 1));
            mt = fmaxf(mt, __shfl_xor(mt, 2));
            mt = fmaxf(mt, __shfl_xor(mt, 4));
            mt = fmaxf(mt, __shfl_xor(mt, 8));
            const float mnew = fmaxf(m_run[r], mt);
            const float sc = __expf(m_run[r] - mnew);
            m_run[r] = mnew;
            float rs = 0.f;
#pragma unroll
            for (int nb = 0; nb < 4; ++nb) {
                const float p = __expf(s[nb][r] - mnew);
                s[nb][r] = p;
                rs += p;
            }
            rs += __shfl_xor(rs, 1);
            rs += __shfl_xor(rs, 2);
            rs += __shfl_xor(rs, 4);
            rs += __shfl_xor(rs, 8);
            l_run[r] = l_run[r] * sc + rs;
#pragma unroll
            for (int nb = 0; nb < 4; ++nb) { accR[nb][r] *= sc; accI[nb][r] *= sc; }
        }

        // P -> LDS (wave-private), then PV
#pragma unroll
        for (int nb = 0; nb < 4; ++nb)
#pragma unroll
            for (int r = 0; r < 4; ++r)
                sP[w][(g * 4 + r) * 68 + nb * 16 + wl] = f2bf(s[nb][r]);

        bf16x8 ap[2];
#pragma unroll
        for (int ks = 0; ks < 2; ++ks)
            ap[ks] = *(const bf16x8*)&sP[w][wl * 68 + ks * 32 + g * 8];
        __builtin_amdgcn_s_setprio(1);
#pragma unroll
        for (int nb = 0; nb < 4; ++nb) {
#pragma unroll
            for (int ks = 0; ks < 2; ++ks) {
                const bf16x8 bvr = *(const bf16x8*)&sV[0][(nb * 16 + wl) * 66 + ks * 32 + g * 8];
                const bf16x8 bvi = *(const bf16x8*)&sV[1][(nb * 16 + wl) * 66 + ks * 32 + g * 8];
                accR[nb] = __builtin_amdgcn_mfma_f32_16x16x32_bf16(ap[ks], bvr, accR[nb], 0, 0, 0);
                accI[nb] = __builtin_amdgcn_mfma_f32_16x16x32_bf16(ap[ks], bvi, accI[nb], 0, 0, 0);
            }
        }
        __builtin_amdgcn_s_setprio(0);
    }

    // epilogue
    float inv[4];
#pragma unroll
    for (int r = 0; r < 4; ++r) inv[r] = 1.0f / l_run[r];
#pragma unroll
    for (int nb = 0; nb < 4; ++nb) {
#pragma unroll
        for (int r = 0; r < 4; ++r) {
            const int q = qt * 128 + w * 16 + g * 4 + r;
            const int d = nb * 16 + wl;
            const size_t base = ((size_t)(b * T_) + q) * KC_ + h * 64 + d;
            otc[base] = f2bf(accR[nb][r] * inv[r]);
            otc[base + 1024] = f2bf(accI[nb][r] * inv[r]);
        }
    }
}

// ---------------------------------------------------------------- launch
extern "C" void kernel_launch(void* const* d_in, const int* in_sizes, int n_in,
                              void* d_out, int out_size, void* d_ws, size_t ws_size,
                              hipStream_t stream) {
    const float* x_r  = (const float*)d_in[0];
    const float* x_i  = (const float*)d_in[1];
    const float* lat  = (const float*)d_in[2];
    const float* lon  = (const float*)d_in[3];
    const float* q_lm = (const float*)d_in[4];
    const float* q_ph = (const float*)d_in[5];
    const float* q_bm = (const float*)d_in[6];
    const float* q_bp = (const float*)d_in[7];
    const float* k_lm = (const float*)d_in[8];
    const float* k_ph = (const float*)d_in[9];
    const float* k_bm = (const float*)d_in[10];
    const float* k_bp = (const float*)d_in[11];
    const float* v_lm = (const float*)d_in[12];
    const float* v_ph = (const float*)d_in[13];
    const float* v_bm = (const float*)d_in[14];
    const float* v_bp = (const float*)d_in[15];
    const float* o_lm = (const float*)d_in[16];
    const float* o_ph = (const float*)d_in[17];
    const float* o_bm = (const float*)d_in[18];
    const float* o_bp = (const float*)d_in[19];
    const float* dsc  = (const float*)d_in[20];
    const float* dof  = (const float*)d_in[21];

    char* ws = (char*)d_ws;
    const size_t MB = 1024u * 1024u;
    short* Wv  = (short*)(ws + 0 * MB);     // 8 MB
    short* Wo  = (short*)(ws + 8 * MB);     // 8 MB
    short* Wqh = (short*)(ws + 16 * MB);    // 8 MB
    short* Wql = (short*)(ws + 24 * MB);
    short* Wkh = (short*)(ws + 32 * MB);
    short* Wkl = (short*)(ws + 40 * MB);
    short* xch = (short*)(ws + 48 * MB);    // 16 MB
    short* xcl = (short*)(ws + 64 * MB);    // 16 MB
    short* qhh = (short*)(ws + 80 * MB);    // 16 MB
    short* qll = (short*)(ws + 96 * MB);
    short* khh = (short*)(ws + 112 * MB);
    short* kll = (short*)(ws + 128 * MB);
    short* vcb = (short*)(ws + 144 * MB);   // 16 MB
    short* otc = (short*)(ws + 160 * MB);   // 16 MB
    short* ldt = (short*)(ws + 176 * MB);   // B*T*T bf16, 8 MB

    wgen_all<<<4 * 4096, 256, 0, stream>>>(q_lm, q_ph, k_lm, k_ph, v_lm, v_ph, o_lm, o_ph,
                                           Wqh, Wql, Wkh, Wkl, Wv, Wo);
    xcat_split<<<BTE / 256, 256, 0, stream>>>(x_r, x_i, xch, xcl);
    geodist<<<BTT / 256, 256, 0, stream>>>(lat, lon, ldt);

    cgemm_qk2<<<256, 512, 0, stream>>>(xch, xcl, Wqh, Wql, Wkh, Wkl,
                                       q_bm, q_bp, k_bm, k_bp,
                                       qhh, qll, khh, kll);

    dim3 ggrid(M_ / 128, KC_ / 128);
    cgemm_mfma<<<ggrid, 256, 0, stream>>>(xch, Wv, v_bm, v_bp, vcb, nullptr, nullptr, 0);

    attn_split<<<512, 512, 0, stream>>>(qhh, qll, khh, kll, vcb, ldt, dsc, dof, otc);

    float* yr = (float*)d_out;
    float* yi = (float*)d_out + BTE;
    cgemm_mfma<<<ggrid, 256, 0, stream>>>(otc, Wo, o_bm, o_bp, nullptr, yr, yi, 1);
}